// Round 8
// baseline (483.259 us; speedup 1.0000x reference)
//
#include <hip/hip_runtime.h>
#include <hip/hip_bf16.h>
#include <stdint.h>

#define NE   64
#define DIM  1024
#define HID  512
#define TPE  1024   // tokens per expert (uniform in this problem)

typedef __attribute__((ext_vector_type(8)))  __bf16          bf16x8;
typedef __attribute__((ext_vector_type(4)))  float           f32x4;
typedef __attribute__((ext_vector_type(16))) float           f32x16;
typedef __attribute__((ext_vector_type(8)))  unsigned short  ushort8_t;
typedef __attribute__((ext_vector_type(4)))  unsigned short  ushort4_t;
typedef __attribute__((ext_vector_type(4)))  float           float4_t;

__device__ __forceinline__ unsigned short f2bf(float f) {
  return __builtin_bit_cast(unsigned short, static_cast<__bf16>(f));  // RNE
}
__device__ __forceinline__ float bf2f(unsigned short u) {
  unsigned int x = ((unsigned int)u) << 16;
  return __builtin_bit_cast(float, x);
}
__device__ __forceinline__ ushort8_t pack8(float4_t a, float4_t b) {
  ushort8_t r;
  r[0] = f2bf(a[0]); r[1] = f2bf(a[1]); r[2] = f2bf(a[2]); r[3] = f2bf(a[3]);
  r[4] = f2bf(b[0]); r[5] = f2bf(b[1]); r[6] = f2bf(b[2]); r[7] = f2bf(b[3]);
  return r;
}
__device__ __forceinline__ bf16x8 ldsfrag(const unsigned short* p) {
  return __builtin_bit_cast(bf16x8, *reinterpret_cast<const ushort8_t*>(p));
}
__device__ __forceinline__ void barrier_lgkm() {
  asm volatile("s_waitcnt lgkmcnt(0)" ::: "memory");
  __builtin_amdgcn_s_barrier();
}
// global -> LDS direct (16 B/lane). LDS dest must be wave-uniform base;
// global src is per-lane (pre-swizzled).
typedef __attribute__((address_space(1))) const unsigned int gas_uint;
typedef __attribute__((address_space(3))) unsigned int las_uint;
__device__ __forceinline__ void gload16(const void* g, void* l) {
  __builtin_amdgcn_global_load_lds((gas_uint*)g, (las_uint*)l, 16, 0, 0);
}

#define LDK 40   // fallback kernels' padded LDS stride

__device__ __forceinline__ int xcd_swizzle(int bid, int nwg) {
  return (bid & 7) * (nwg >> 3) + (bid >> 3);
}

// ===========================================================================
// FAST PATH (requires ws >= 384 MiB):
//   conv: X,W1||W3,W2 fp32 -> bf16 in ws
//   p1/p2: 256x256 BK=64 8-wave GEMM, global_load_lds + swizzled reads,
//          4 phases/K-tile, raw barriers, full-tile-flight staging.
// ===========================================================================

// --- conversion kernel -----------------------------------------------------
// chunk = 8 elems. X: 8388608 chunks; WB13 (stacked [e][g][256][1024]):
// 8388608; W2b: 4194304. Total 20971520.
__global__ __launch_bounds__(256) void conv_kernel(
    const float* __restrict__ X, const float* __restrict__ W1,
    const float* __restrict__ W3, const float* __restrict__ W2,
    unsigned short* __restrict__ Xb, unsigned short* __restrict__ WB13,
    unsigned short* __restrict__ W2b) {
  const long long total = 20971520LL;
  const long long stride = (long long)gridDim.x * blockDim.x;
  for (long long c = blockIdx.x * (long long)blockDim.x + threadIdx.x;
       c < total; c += stride) {
    const float* src;
    unsigned short* dst;
    if (c < 8388608LL) {                       // X
      src = X + c * 8;
      dst = Xb + c * 8;
    } else if (c < 16777216LL) {               // W1||W3 stacked per (e,g)
      const long long d = c - 8388608LL;
      const int eg = (int)(d >> 15);           // e*4+g
      const int rem = (int)(d & 32767);
      const int r = rem >> 7, c8 = rem & 127;
      const int e = eg >> 2, g = eg & 3;
      if (r < 128) src = W1 + ((size_t)e * HID + g * 128 + r) * DIM + c8 * 8;
      else         src = W3 + ((size_t)e * HID + g * 128 + (r - 128)) * DIM + c8 * 8;
      dst = WB13 + d * 8;
    } else {                                   // W2
      const long long d = c - 16777216LL;
      src = W2 + d * 8;
      dst = W2b + d * 8;
    }
    float4_t v0 = *reinterpret_cast<const float4_t*>(src);
    float4_t v1 = *reinterpret_cast<const float4_t*>(src + 4);
    *reinterpret_cast<ushort8_t*>(dst) = pack8(v0, v1);
  }
}

// --- shared GEMM-core machinery --------------------------------------------
// Tile 256x256, BK=64. LDS: [2 buf][A|B][256 rows][64 cols] bf16 = 128 KiB.
// Row = 128 B. Swizzle: 16B-col c16' = c16 ^ (row&7); gload_lds source is
// pre-swizzled (inverse == same XOR), reads apply the XOR -> conflict-free.
// Stage: per tile 64 KB = 64 gload_lds; per wave 8 (4 A + 4 B), 2 per phase.
// 4 phases/K-tile: q=(kk,nh): [ds_read frags | 2 stage] barrier [16 MFMA].
// vmcnt(0)+barrier once per tile; stage has a full tile (~1000cy) of flight.

#define GEMM_CORE(NT, A_ROWLEN, B_ROWLEN, gA, gB, smem)                        \
  const int lane = threadIdx.x & 63;                                          \
  const int wid  = threadIdx.x >> 6;                                          \
  const int wr   = wid >> 2, wn = wid & 3; /* 2M x 4N waves */                \
  const int fr   = lane & 15;                                                 \
  const int c16b = lane >> 4;                                                 \
  const int swz  = fr & 7;                                                    \
  const int s_r  = lane >> 3;          /* stage: lane's row within 8 */       \
  const int s_c  = ((lane & 7) ^ s_r) * 8; /* pre-swizzled src col (elems) */ \
  f32x4 acc[8][4];                                                            \
  _Pragma("unroll") for (int m = 0; m < 8; ++m)                               \
    _Pragma("unroll") for (int n = 0; n < 4; ++n)                             \
      _Pragma("unroll") for (int i = 0; i < 4; ++i) acc[m][n][i] = 0.f;       \
  auto stA = [&](int buf, int kt, int j) {                                    \
    gload16(gA + (size_t)(j * 8 + s_r) * A_ROWLEN + kt * 64 + s_c,            \
            &smem[buf][0][j * 512]);                                          \
  };                                                                          \
  auto stB = [&](int buf, int kt, int j) {                                    \
    gload16(gB + (size_t)(j * 8 + s_r) * B_ROWLEN + kt * 64 + s_c,            \
            &smem[buf][1][j * 512]);                                          \
  };                                                                          \
  auto rdA = [&](int buf, int m, int kk) {                                    \
    const int row = wr * 128 + m * 16 + fr;                                   \
    return ldsfrag(&smem[buf][0][row * 64 + (((c16b + kk * 4) ^ swz) * 8)]);  \
  };                                                                          \
  auto rdB = [&](int buf, int nf, int kk) {                                   \
    const int row = wn * 64 + nf * 16 + fr;                                   \
    return ldsfrag(&smem[buf][1][row * 64 + (((c16b + kk * 4) ^ swz) * 8)]);  \
  };                                                                          \
  _Pragma("unroll 1") for (int j = 0; j < 4; ++j) { stA(0, 0, wid * 4 + j); } \
  _Pragma("unroll 1") for (int j = 0; j < 4; ++j) { stB(0, 0, wid * 4 + j); } \
  for (int kt = 0; kt < NT; ++kt) {                                           \
    const int buf = kt & 1, sbuf = buf ^ 1;                                   \
    const bool st = (kt + 1 < NT);                                            \
    asm volatile("s_waitcnt vmcnt(0)" ::: "memory");                          \
    __builtin_amdgcn_s_barrier();                                             \
    asm volatile("" ::: "memory");                                            \
    bf16x8 af[8];                                                             \
    _Pragma("unroll") for (int q = 0; q < 4; ++q) {                           \
      const int kk = q >> 1, nh = q & 1;                                      \
      if (nh == 0) {                                                          \
        _Pragma("unroll") for (int m = 0; m < 8; ++m) af[m] = rdA(buf, m, kk);\
      }                                                                       \
      bf16x8 bf0 = rdB(buf, nh * 2 + 0, kk);                                  \
      bf16x8 bf1 = rdB(buf, nh * 2 + 1, kk);                                  \
      if (st) {                                                               \
        if (q < 2) { stA(sbuf, kt + 1, wid * 4 + q * 2);                      \
                     stA(sbuf, kt + 1, wid * 4 + q * 2 + 1); }                \
        else       { stB(sbuf, kt + 1, wid * 4 + (q - 2) * 2);                \
                     stB(sbuf, kt + 1, wid * 4 + (q - 2) * 2 + 1); }          \
      }                                                                       \
      asm volatile("" ::: "memory");                                          \
      __builtin_amdgcn_s_barrier();                                           \
      __builtin_amdgcn_s_setprio(1);                                          \
      _Pragma("unroll") for (int m = 0; m < 8; ++m) {                         \
        acc[m][nh * 2 + 0] = __builtin_amdgcn_mfma_f32_16x16x32_bf16(         \
            af[m], bf0, acc[m][nh * 2 + 0], 0, 0, 0);                         \
        acc[m][nh * 2 + 1] = __builtin_amdgcn_mfma_f32_16x16x32_bf16(         \
            af[m], bf1, acc[m][nh * 2 + 1], 0, 0, 0);                         \
      }                                                                       \
      __builtin_amdgcn_s_setprio(0);                                          \
    }                                                                         \
  }

// --- p1: H = bf16( silu(X@W1^T) * (X@W3^T) ) -------------------------------
// B-tile = 256 stacked rows: [128 W1-rows ; 128 W3-rows] of hid-group g.
// Waves wn<2 hold W1-results, wn>=2 matching W3-results; epilogue exchanges
// the W3 half via LDS (overlaid on the staging buffers).
__global__ __launch_bounds__(512, 2) void p1_fast(
    const unsigned short* __restrict__ Xb, const unsigned short* __restrict__ WB13,
    unsigned short* __restrict__ H) {
  __shared__ __align__(16) unsigned short smem[2][2][256 * 64];  // 128 KiB

  const int tile = xcd_swizzle(blockIdx.x, NE * 4 * 4);
  const int e  = tile >> 4;
  const int g  = (tile >> 2) & 3;    // hid-group (128 channels)
  const int tm = tile & 3;           // inner: WB13 slab L2-hot
  const unsigned short* gA = Xb   + (size_t)(e * TPE + tm * 256) * DIM;
  const unsigned short* gB = WB13 + (size_t)(e * 4 + g) * 256 * DIM;

  GEMM_CORE(16, DIM, DIM, gA, gB, smem)

  // epilogue: exchange W3 half through LDS, combine in W1 waves.
  __builtin_amdgcn_s_barrier();      // all frag reads done; reuse smem
  unsigned short* bex = &smem[0][0][0];   // [128 hid][264 tok] bf16 = 67.5 KB
  const int q4 = (lane >> 4) * 4;
  if (wn >= 2) {
#pragma unroll
    for (int m = 0; m < 8; ++m)
#pragma unroll
      for (int n = 0; n < 4; ++n) {
        const int hidl = (wn - 2) * 64 + n * 16 + fr;
        const int tokl = wr * 128 + m * 16 + q4;
        ushort4_t v;
#pragma unroll
        for (int r = 0; r < 4; ++r) v[r] = f2bf(acc[m][n][r]);
        *reinterpret_cast<ushort4_t*>(&bex[hidl * 264 + tokl]) = v;
      }
  }
  barrier_lgkm();
  if (wn < 2) {
    const int rowbase = e * TPE + tm * 256;
#pragma unroll
    for (int m = 0; m < 8; ++m)
#pragma unroll
      for (int n = 0; n < 4; ++n) {
        const int hidl = wn * 64 + n * 16 + fr;
        const int tokl = wr * 128 + m * 16 + q4;
        const ushort4_t bv =
            *reinterpret_cast<const ushort4_t*>(&bex[hidl * 264 + tokl]);
#pragma unroll
        for (int r = 0; r < 4; ++r) {
          const float av = bf2f(f2bf(acc[m][n][r]));   // ref bf16 rounding
          const float b  = bf2f(bv[r]);
          const float s  = av / (1.0f + __expf(-av));
          H[(size_t)(rowbase + tokl + r) * HID + g * 128 + hidl] = f2bf(s * b);
        }
      }
  }
}

// --- p2: OUT = fp32( bf16( H @ W2b^T ) ) -----------------------------------
__global__ __launch_bounds__(512, 2) void p2_fast(
    const unsigned short* __restrict__ Hb, const unsigned short* __restrict__ W2b,
    float* __restrict__ OUT) {
  __shared__ __align__(16) unsigned short smem[2][2][256 * 64];  // 128 KiB

  const int tile = xcd_swizzle(blockIdx.x, NE * 4 * 4);
  const int e  = tile >> 4;
  const int tn = (tile >> 2) & 3;    // dim-tile of 256
  const int tm = tile & 3;           // inner: W2b slab L2-hot
  const unsigned short* gA = Hb  + (size_t)(e * TPE + tm * 256) * HID;
  const unsigned short* gB = W2b + (size_t)(e * DIM + tn * 256) * HID;

  GEMM_CORE(8, HID, HID, gA, gB, smem)

  const int q4 = (lane >> 4) * 4;
  const int rowbase = e * TPE + tm * 256;
#pragma unroll
  for (int m = 0; m < 8; ++m)
#pragma unroll
    for (int n = 0; n < 4; ++n) {
      const int d    = tn * 256 + wn * 64 + n * 16 + fr;
      const int tokl = wr * 128 + m * 16 + q4;
#pragma unroll
      for (int r = 0; r < 4; ++r)
        OUT[(size_t)(rowbase + tokl + r) * DIM + d] = bf2f(f2bf(acc[m][n][r]));
    }
}

// ===========================================================================
// FALLBACK PATH (R7 kernels, proven): used when ws_size < 384 MiB.
// ===========================================================================
#define P1_NKT (DIM / 32)

__global__ __launch_bounds__(256, 3) void p1_fb(
    const float* __restrict__ X, const float* __restrict__ W1,
    const float* __restrict__ W3, unsigned short* __restrict__ H) {
  __shared__ __align__(16) unsigned short lA[2][128 * LDK];
  __shared__ __align__(16) unsigned short lB[2][128 * LDK];

  const int tile = xcd_swizzle(blockIdx.x, NE * 8 * 8);
  const int e  = tile >> 6;
  const int tn = (tile >> 3) & 7;
  const int tm = tile & 7;
  const int t  = threadIdx.x;

  const float* gA  = X  + (size_t)(e * TPE + tm * 128) * DIM;
  const float* gW1 = W1 + ((size_t)e * HID + tn * 64) * DIM;
  const float* gW3 = W3 + ((size_t)e * HID + tn * 64) * DIM;
  const int ar = t >> 2, ac = (t & 3) * 8;

  float4_t a0[2][2], a1[2][2], bb[2][2];
  auto load_gA = [&](float4_t (&a)[2][2], int kt) {
#pragma unroll
    for (int i = 0; i < 2; ++i) {
      const size_t o = (size_t)(ar + 64 * i) * DIM + kt * 32 + ac;
      a[i][0] = *reinterpret_cast<const float4_t*>(gA + o);
      a[i][1] = *reinterpret_cast<const float4_t*>(gA + o + 4);
    }
  };
  auto load_gB = [&](int kt) {
    const size_t o = (size_t)ar * DIM + kt * 32 + ac;
    bb[0][0] = *reinterpret_cast<const float4_t*>(gW1 + o);
    bb[0][1] = *reinterpret_cast<const float4_t*>(gW1 + o + 4);
    bb[1][0] = *reinterpret_cast<const float4_t*>(gW3 + o);
    bb[1][1] = *reinterpret_cast<const float4_t*>(gW3 + o + 4);
  };
  auto store_lA = [&](int buf, float4_t (&a)[2][2]) {
#pragma unroll
    for (int i = 0; i < 2; ++i)
      *reinterpret_cast<ushort8_t*>(&lA[buf][(ar + 64 * i) * LDK + ac]) =
          pack8(a[i][0], a[i][1]);
  };
  auto store_lB = [&](int buf) {
    *reinterpret_cast<ushort8_t*>(&lB[buf][ar * LDK + ac]) = pack8(bb[0][0], bb[0][1]);
    *reinterpret_cast<ushort8_t*>(&lB[buf][(ar + 64) * LDK + ac]) = pack8(bb[1][0], bb[1][1]);
  };

  const int lane = t & 63, wv = t >> 6, lr = lane & 31, ks = (lane >> 5) * 8;
  f32x16 acc[4];
#pragma unroll
  for (int n = 0; n < 4; ++n)
#pragma unroll
    for (int i = 0; i < 16; ++i) acc[n][i] = 0.f;

  auto mfma_phase = [&](int buf) {
#pragma unroll
    for (int kk = 0; kk < 2; ++kk) {
      const bf16x8 af = ldsfrag(&lA[buf][(wv * 32 + lr) * LDK + kk * 16 + ks]);
#pragma unroll
      for (int n = 0; n < 4; ++n) {
        const bf16x8 bf = ldsfrag(&lB[buf][(n * 32 + lr) * LDK + kk * 16 + ks]);
        acc[n] = __builtin_amdgcn_mfma_f32_32x32x16_bf16(af, bf, acc[n], 0, 0, 0);
      }
    }
  };

  load_gA(a0, 0); load_gB(0); load_gA(a1, 1);
  for (int kt = 0; kt < P1_NKT; kt += 2) {
    store_lA(0, a0); store_lB(0);
    if (kt + 2 < P1_NKT) load_gA(a0, kt + 2);
    load_gB(kt + 1);
    barrier_lgkm();
    mfma_phase(0);
    store_lA(1, a1); store_lB(1);
    if (kt + 3 < P1_NKT) load_gA(a1, kt + 3);
    if (kt + 2 < P1_NKT) load_gB(kt + 2);
    barrier_lgkm();
    mfma_phase(1);
  }
  const int tokBase = e * TPE + tm * 128 + wv * 32;
  const int hidBase = tn * 64;
  const int ks4 = (lane >> 5) * 4;
#pragma unroll
  for (int n = 0; n < 2; ++n)
#pragma unroll
    for (int r = 0; r < 16; ++r) {
      const int rr = (r & 3) + 8 * (r >> 2) + ks4;
      const int tok = tokBase + rr;
      const int hid = hidBase + n * 32 + lr;
      const float av = bf2f(f2bf(acc[n][r]));
      const float bv = bf2f(f2bf(acc[n + 2][r]));
      const float s = av / (1.0f + __expf(-av));
      H[(size_t)tok * HID + hid] = f2bf(s * bv);
    }
}

#define P2_NKT (HID / 32)

__global__ __launch_bounds__(256, 3) void p2_fb(
    const unsigned short* __restrict__ Hin, const float* __restrict__ W2,
    float* __restrict__ OUT) {
  __shared__ __align__(16) unsigned short lA[2][128 * LDK];
  __shared__ __align__(16) unsigned short lB[2][128 * LDK];

  const int tile = xcd_swizzle(blockIdx.x, NE * 8 * 8);
  const int e  = tile >> 6;
  const int tn = (tile >> 3) & 7;
  const int tm = tile & 7;
  const int t  = threadIdx.x;

  const unsigned short* gA = Hin + (size_t)(e * TPE + tm * 128) * HID;
  const float*          gB = W2  + ((size_t)e * DIM + tn * 128) * HID;
  const int ar = t >> 2, ac = (t & 3) * 8;

  ushort8_t ha0[2], ha1[2];
  float4_t  wb[2][2];
  auto load_gA = [&](ushort8_t (&ha)[2], int kt) {
#pragma unroll
    for (int i = 0; i < 2; ++i)
      ha[i] = *reinterpret_cast<const ushort8_t*>(
          gA + (size_t)(ar + 64 * i) * HID + kt * 32 + ac);
  };
  auto load_gB = [&](int kt) {
#pragma unroll
    for (int i = 0; i < 2; ++i) {
      const size_t o = (size_t)(ar + 64 * i) * HID + kt * 32 + ac;
      wb[i][0] = *reinterpret_cast<const float4_t*>(gB + o);
      wb[i][1] = *reinterpret_cast<const float4_t*>(gB + o + 4);
    }
  };
  auto store_lA = [&](int buf, ushort8_t (&ha)[2]) {
#pragma unroll
    for (int i = 0; i < 2; ++i)
      *reinterpret_cast<ushort8_t*>(&lA[buf][(ar + 64 * i) * LDK + ac]) = ha[i];
  };
  auto store_lB = [&](int buf) {
#pragma unroll
    for (int i = 0; i < 2; ++i)
      *reinterpret_cast<ushort8_t*>(&lB[buf][(ar + 64 * i) * LDK + ac]) =
          pack8(wb[i][0], wb[i][1]);
  };

  const int lane = t & 63, wv = t >> 6, lr = lane & 31, ks = (lane >> 5) * 8;
  f32x16 acc[4];
#pragma unroll
  for (int n = 0; n < 4; ++n)
#pragma unroll
    for (int i = 0; i < 16; ++i) acc[n][i] = 0.f;

  auto mfma_phase = [&](int buf) {
#pragma unroll
    for (int kk = 0; kk < 2; ++kk) {
      const bf16x8 af = ldsfrag(&lA[buf][(wv * 32 + lr) * LDK + kk * 16 + ks]);
#pragma unroll
      for (int n = 0; n < 4; ++n) {
        const bf16x8 bf = ldsfrag(&lB[buf][(n * 32 + lr) * LDK + kk * 16 + ks]);
        acc[n] = __builtin_amdgcn_mfma_f32_32x32x16_bf16(af, bf, acc[n], 0, 0, 0);
      }
    }
  };

  load_gA(ha0, 0); load_gB(0); load_gA(ha1, 1);
  for (int kt = 0; kt < P2_NKT; kt += 2) {
    store_lA(0, ha0); store_lB(0);
    if (kt + 2 < P2_NKT) load_gA(ha0, kt + 2);
    load_gB(kt + 1);
    barrier_lgkm();
    mfma_phase(0);
    store_lA(1, ha1); store_lB(1);
    if (kt + 3 < P2_NKT) load_gA(ha1, kt + 3);
    if (kt + 2 < P2_NKT) load_gB(kt + 2);
    barrier_lgkm();
    mfma_phase(1);
  }
  const int tokBase = e * TPE + tm * 128 + wv * 32;
  const int dBase = tn * 128;
  const int ks4 = (lane >> 5) * 4;
#pragma unroll
  for (int n = 0; n < 4; ++n)
#pragma unroll
    for (int r = 0; r < 16; ++r) {
      const int rr = (r & 3) + 8 * (r >> 2) + ks4;
      OUT[(size_t)(tokBase + rr) * DIM + dBase + n * 32 + lr] =
          bf2f(f2bf(acc[n][r]));
    }
}

// ---------------------------------------------------------------------------
extern "C" void kernel_launch(void* const* d_in, const int* in_sizes, int n_in,
                              void* d_out, int out_size, void* d_ws, size_t ws_size,
                              hipStream_t stream) {
  (void)in_sizes; (void)n_in; (void)out_size;
  const float* X  = (const float*)d_in[0];
  const float* W1 = (const float*)d_in[1];
  const float* W2 = (const float*)d_in[2];
  const float* W3 = (const float*)d_in[3];
  float* OUT = (float*)d_out;

  const size_t MiB = 1024 * 1024;
  if (ws_size >= 384 * MiB) {
    unsigned short* Xb   = (unsigned short*)d_ws;                  // 128 MiB
    unsigned short* WB13 = Xb + (size_t)128 * MiB / 2;             // 128 MiB
    unsigned short* W2b  = Xb + (size_t)256 * MiB / 2;             //  64 MiB
    unsigned short* H    = Xb + (size_t)320 * MiB / 2;             //  64 MiB
    conv_kernel<<<dim3(2048), dim3(256), 0, stream>>>(X, W1, W3, W2,
                                                      Xb, WB13, W2b);
    p1_fast<<<dim3(NE * 4 * 4), dim3(512), 0, stream>>>(Xb, WB13, H);
    p2_fast<<<dim3(NE * 4 * 4), dim3(512), 0, stream>>>(H, W2b, OUT);
  } else {
    unsigned short* H = (unsigned short*)d_ws;                     // 64 MiB
    p1_fb<<<dim3(NE * 8 * 8), dim3(256), 0, stream>>>(X, W1, W3, H);
    p2_fb<<<dim3(NE * 8 * 8), dim3(256), 0, stream>>>(H, W2, OUT);
  }
}